// Round 13
// baseline (989.496 us; speedup 1.0000x reference)
//
#include <hip/hip_runtime.h>
#include <hip/hip_bf16.h>
#include <math.h>

// Problem constants (fixed by the reference)
#define BB 32      // batch
#define SS 2048    // seq len
#define DD 64      // dim_s
#define MM 32      // size_m
#define NSKILL 4096
#define CC 64      // scan chunks
#define LL 32      // chunk length = SS/CC
#define NOUT (BB * (SS - 1))   // 65504

__device__ __forceinline__ float sigmoidf_(float x) {
    return 1.f / (1.f + __expf(-x));
}
__device__ __forceinline__ float tanhf_(float x) {
    float t = __expf(-2.f * fabsf(x));
    float r = (1.f - t) / (1.f + t);
    return copysignf(r, x);
}

// ---------------------------------------------------------------------------
// Kernel 1 (k_front v3): identical to v2 except __launch_bounds__(256, 2).
// v2's (256,3) clamped VGPR to 84 < ~130 live set -> full scratch spill
// (FETCH 460MB, WRITE 888MB, 623us). (256,2) caps at 256 VGPR: no spill;
// occupancy now LDS-limited at ~4-6 blocks/CU (25KB/block).
// ---------------------------------------------------------------------------
__global__ __launch_bounds__(256, 2) void k_front(
    const int* __restrict__ skill, const int* __restrict__ resp,
    const float* __restrict__ k_emb, const float* __restrict__ v_emb,
    const float* __restrict__ Mk,
    const float* __restrict__ eW, const float* __restrict__ eb,
    const float* __restrict__ aW, const float* __restrict__ ab,
    const float* __restrict__ mask,
    float* __restrict__ w_out, float* __restrict__ e_out, float* __restrict__ a_out,
    float* __restrict__ Abar, float* __restrict__ Bbar)
{
    __shared__ float stage[64 * 64];     // k rows -> v rows -> exchange buf
    __shared__ float w_lds[64 * 32];
    __shared__ float mk_lds[64];
    const int tid = threadIdx.x;
    const int g = blockIdx.x;            // 64-token group
    const int l = tid & 63;
    const int wv = tid >> 6;

    if (tid < 64) mk_lds[tid] = mask[g * 64 + tid];

    // ---- stage k rows (64 x 64) ----
    #pragma unroll
    for (int p = 0; p < 4; ++p) {
        const int r = p * 16 + (tid >> 4);
        const int t = g * 64 + r;
        const float4 kv = ((const float4*)(k_emb + (size_t)skill[t] * DD))[tid & 15];
        *(float4*)&stage[r * 64 + (tid & 15) * 4] = kv;
    }
    __syncthreads();

    // ---- W phase: lane = (m, token-half), 16 tokens per wave ----
    {
        const int m  = l & 31;
        const int th = l >> 5;
        float4 mk4[16];
        const float4* mkp = (const float4*)(Mk + m * DD);
        #pragma unroll
        for (int q = 0; q < 16; ++q) mk4[q] = mkp[q];

        for (int j = 0; j < 8; ++j) {
            const int tl = wv * 16 + j * 2 + th;
            const float4* kp = (const float4*)&stage[tl * 64];
            float a0 = 0.f, a1 = 0.f, a2 = 0.f, a3 = 0.f;
            #pragma unroll
            for (int q = 0; q < 16; ++q) {
                const float4 kv = kp[q];                 // uniform broadcast
                a0 = fmaf(kv.x, mk4[q].x, a0);
                a1 = fmaf(kv.y, mk4[q].y, a1);
                a2 = fmaf(kv.z, mk4[q].z, a2);
                a3 = fmaf(kv.w, mk4[q].w, a3);
            }
            const float lg = (a0 + a1) + (a2 + a3);
            float mx = lg;
            #pragma unroll
            for (int off = 16; off >= 1; off >>= 1) mx = fmaxf(mx, __shfl_xor(mx, off));
            const float ev = __expf(lg - mx);
            float sm = ev;
            #pragma unroll
            for (int off = 16; off >= 1; off >>= 1) sm += __shfl_xor(sm, off);
            w_lds[tl * 32 + m] = ev / sm;
        }
    }
    __syncthreads();   // w_lds complete; all waves done reading k-stage

    // coalesced global store of w (2048 floats)
    #pragma unroll
    for (int i = 0; i < 8; ++i) {
        const int idx = i * 256 + tid;
        w_out[(size_t)g * 2048 + idx] = w_lds[idx];
    }

    // ---- stage v rows (overwrite k-stage) ----
    #pragma unroll
    for (int p = 0; p < 4; ++p) {
        const int r = p * 16 + (tid >> 4);
        const int t = g * 64 + r;
        const int xc = skill[t] + NSKILL * resp[t];
        const float4 vv = ((const float4*)(v_emb + (size_t)xc * DD))[tid & 15];
        *(float4*)&stage[r * 64 + (tid & 15) * 4] = vv;
    }
    __syncthreads();

    // ---- EA phase: lane = d; tokens wv*16..wv*16+15; results -> registers ----
    float er[16], ar[16];
    {
        float wcol[64];
        #pragma unroll
        for (int i = 0; i < 64; ++i) wcol[i] = eW[i * DD + l];   // coalesced
        const float ebd = eb[l];
        #pragma unroll
        for (int j = 0; j < 16; ++j) {
            const int tl = wv * 16 + j;
            const float4* vp = (const float4*)&stage[tl * 64];
            float e0 = ebd, e1 = 0.f, e2 = 0.f, e3 = 0.f;
            #pragma unroll
            for (int q = 0; q < 16; ++q) {
                const float4 vv = vp[q];                 // uniform broadcast
                e0 = fmaf(vv.x, wcol[4*q+0], e0);
                e1 = fmaf(vv.y, wcol[4*q+1], e1);
                e2 = fmaf(vv.z, wcol[4*q+2], e2);
                e3 = fmaf(vv.w, wcol[4*q+3], e3);
            }
            er[j] = sigmoidf_((e0 + e1) + (e2 + e3));
            e_out[(size_t)(g * 64 + tl) * DD + l] = er[j];   // 256B contiguous
        }
        #pragma unroll
        for (int i = 0; i < 64; ++i) wcol[i] = aW[i * DD + l];  // reuse regs
        const float abd = ab[l];
        #pragma unroll
        for (int j = 0; j < 16; ++j) {
            const int tl = wv * 16 + j;
            const float4* vp = (const float4*)&stage[tl * 64];
            float x0 = abd, x1 = 0.f, x2 = 0.f, x3 = 0.f;
            #pragma unroll
            for (int q = 0; q < 16; ++q) {
                const float4 vv = vp[q];
                x0 = fmaf(vv.x, wcol[4*q+0], x0);
                x1 = fmaf(vv.y, wcol[4*q+1], x1);
                x2 = fmaf(vv.z, wcol[4*q+2], x2);
                x3 = fmaf(vv.w, wcol[4*q+3], x3);
            }
            ar[j] = tanhf_((x0 + x1) + (x2 + x3));
            a_out[(size_t)(g * 64 + tl) * DD + l] = ar[j];
        }
    }

    // ---- Compose phase: wave wv = half-chunk (ch = wv>>1, hf = wv&1);
    //      its tokens are exactly er/ar's tokens. ----
    float Ab[32], Bb[32];
    #pragma unroll
    for (int i = 0; i < 32; ++i) { Ab[i] = 1.f; Bb[i] = 0.f; }

    #pragma unroll
    for (int j = 0; j < 16; ++j) {
        const int t = wv * 16 + j;
        const float ed = er[j];
        const float ad = ar[j];
        const float msk = (mk_lds[t] == 1.f) ? 1.f : 0.f;
        const float4* wr = (const float4*)&w_lds[t * 32];
        #pragma unroll
        for (int u = 0; u < 8; ++u) {
            float4 wq = wr[u];                           // uniform broadcast
            wq.x *= msk; wq.y *= msk; wq.z *= msk; wq.w *= msk;
            float t1;
            t1 = fmaf(-wq.x, ed, 1.f); Ab[4*u+0] *= t1; Bb[4*u+0] = fmaf(Bb[4*u+0], t1, wq.x * ad);
            t1 = fmaf(-wq.y, ed, 1.f); Ab[4*u+1] *= t1; Bb[4*u+1] = fmaf(Bb[4*u+1], t1, wq.y * ad);
            t1 = fmaf(-wq.z, ed, 1.f); Ab[4*u+2] *= t1; Bb[4*u+2] = fmaf(Bb[4*u+2], t1, wq.z * ad);
            t1 = fmaf(-wq.w, ed, 1.f); Ab[4*u+3] *= t1; Bb[4*u+3] = fmaf(Bb[4*u+3], t1, wq.w * ad);
        }
    }
    __syncthreads();   // v-stage dead; safe to reuse as exchange buffer

    // ---- exchange: combine (first∘second): A=Aa*Ab, B=Ba*Ab+Bb ----
    // chunk 0 (waves 0->1), then chunk 1 (waves 2->3) through stage[0:4096]
    if (wv == 0) {
        #pragma unroll
        for (int i = 0; i < 32; ++i) {
            stage[i * 64 + l]        = Ab[i];
            stage[2048 + i * 64 + l] = Bb[i];
        }
    }
    __syncthreads();
    if (wv == 1) {
        const size_t base = ((size_t)g * 2 + 0) * (MM * DD);
        #pragma unroll
        for (int i = 0; i < 32; ++i) {
            const float Aa = stage[i * 64 + l];
            const float Ba = stage[2048 + i * 64 + l];
            Abar[base + i * 64 + l] = Aa * Ab[i];                  // coalesced
            Bbar[base + i * 64 + l] = fmaf(Ba, Ab[i], Bb[i]);
        }
    }
    __syncthreads();
    if (wv == 2) {
        #pragma unroll
        for (int i = 0; i < 32; ++i) {
            stage[i * 64 + l]        = Ab[i];
            stage[2048 + i * 64 + l] = Bb[i];
        }
    }
    __syncthreads();
    if (wv == 3) {
        const size_t base = ((size_t)g * 2 + 1) * (MM * DD);
        #pragma unroll
        for (int i = 0; i < 32; ++i) {
            const float Aa = stage[i * 64 + l];
            const float Ba = stage[2048 + i * 64 + l];
            Abar[base + i * 64 + l] = Aa * Ab[i];
            Bbar[base + i * 64 + l] = fmaf(Ba, Ab[i], Bb[i]);
        }
    }
}

// ---------------------------------------------------------------------------
// Kernel 2 (scan pass 2): sequential over 64 chunks, parallel over B*M*D.
// Unroll x4: batch 8 independent loads per 4 dependent FMAs. Writes
// chunk-start states IN PLACE into Bbar.
// ---------------------------------------------------------------------------
__global__ __launch_bounds__(256, 2) void k_pass2(
    const float* __restrict__ Abar, float* __restrict__ Bbar_cst,
    const float* __restrict__ Mv0)
{
    const int idx = blockIdx.x * 256 + threadIdx.x;   // over B*M*D = 65536
    const int b = idx >> 11;
    const int md = idx & 2047;
    float s = Mv0[md];
    for (int c = 0; c < CC; c += 4) {
        const int o0 = ((b * CC + c) << 11) + md;
        const float sa0 = Abar[o0];
        const float sb0 = Bbar_cst[o0];
        const float sa1 = Abar[o0 + 2048];
        const float sb1 = Bbar_cst[o0 + 2048];
        const float sa2 = Abar[o0 + 4096];
        const float sb2 = Bbar_cst[o0 + 4096];
        const float sa3 = Abar[o0 + 6144];
        const float sb3 = Bbar_cst[o0 + 6144];
        Bbar_cst[o0]        = s; s = fmaf(s, sa0, sb0);
        Bbar_cst[o0 + 2048] = s; s = fmaf(s, sa1, sb1);
        Bbar_cst[o0 + 4096] = s; s = fmaf(s, sa2, sb2);
        Bbar_cst[o0 + 6144] = s; s = fmaf(s, sa3, sb3);
    }
}

// ---------------------------------------------------------------------------
// Kernel 3 (scan pass 3, d-split): 2 blocks per (b,chunk). lane=(m-half, d-off);
// Mv[16]/lane; read partials folded across m-halves with shfl_xor(32).
// ---------------------------------------------------------------------------
__global__ __launch_bounds__(64, 4) void k_pass3(
    const float* __restrict__ w, const float* __restrict__ mask,
    const float* __restrict__ e, const float* __restrict__ a,
    const float* __restrict__ cstate, float* __restrict__ readv)
{
    __shared__ float4 wl[LL * MM / 4];   // masked w  (full 32 m)
    __shared__ float4 wn[LL * MM / 4];   // unmasked w, t+1
    const int lane = threadIdx.x;
    const int bc = blockIdx.x >> 1;
    const int dh = blockIdx.x & 1;
    const int b = bc / CC;
    const int c = bc % CC;
    const int t0 = c * LL;
    const bool last = (c == CC - 1);
    const int dof = lane & 31;
    const int mh  = lane >> 5;

    const float4* wg  = (const float4*)(w + (size_t)(b * SS + t0) * MM);
    const float4* wg2 = (const float4*)(w + (size_t)(b * SS + t0 + 1) * MM);
    #pragma unroll
    for (int u = 0; u < 4; ++u) {
        const int q4 = u * 64 + lane;
        const int j = q4 >> 3;
        const float s = (mask[b * SS + t0 + j] == 1.f) ? 1.f : 0.f;
        float4 wq = wg[q4];
        wq.x *= s; wq.y *= s; wq.z *= s; wq.w *= s;
        wl[q4] = wq;
        float4 wq2;
        if (last && q4 >= 248) wq2 = make_float4(0.f, 0.f, 0.f, 0.f);
        else                   wq2 = wg2[q4];
        wn[q4] = wq2;
    }
    __syncthreads();

    float Mv[16];
    const float* cs = cstate + (size_t)bc * MM * DD + (size_t)(mh * 16) * DD
                      + dh * 32 + dof;
    #pragma unroll
    for (int i = 0; i < 16; ++i) Mv[i] = cs[i * DD];

    const float* ep = e + (size_t)(b * SS + t0) * DD + dh * 32 + dof;
    const float* ap = a + (size_t)(b * SS + t0) * DD + dh * 32 + dof;
    float* ro = readv + (size_t)(b * SS + t0 + 1) * DD + dh * 32 + dof;
    for (int j = 0; j < LL; ++j) {
        const float ed = ep[j * DD];
        const float ad = ap[j * DD];
        const float4* wlj = wl + j * 8 + mh * 4;
        const float4* wnj = wn + j * 8 + mh * 4;
        float r0 = 0.f, r1 = 0.f, r2 = 0.f, r3 = 0.f;
        #pragma unroll
        for (int u = 0; u < 4; ++u) {
            const float4 wq = wlj[u];
            const float4 w2 = wnj[u];
            float t1;
            t1 = fmaf(-wq.x, ed, 1.f); Mv[4*u+0] = fmaf(Mv[4*u+0], t1, wq.x * ad); r0 = fmaf(w2.x, Mv[4*u+0], r0);
            t1 = fmaf(-wq.y, ed, 1.f); Mv[4*u+1] = fmaf(Mv[4*u+1], t1, wq.y * ad); r1 = fmaf(w2.y, Mv[4*u+1], r1);
            t1 = fmaf(-wq.z, ed, 1.f); Mv[4*u+2] = fmaf(Mv[4*u+2], t1, wq.z * ad); r2 = fmaf(w2.z, Mv[4*u+2], r2);
            t1 = fmaf(-wq.w, ed, 1.f); Mv[4*u+3] = fmaf(Mv[4*u+3], t1, wq.w * ad); r3 = fmaf(w2.w, Mv[4*u+3], r3);
        }
        float r = (r0 + r1) + (r2 + r3);
        r += __shfl_xor(r, 32);              // fold the two m-halves
        if (mh == 0 && !(last && j == LL - 1))
            ro[j * DD] = r;
    }
}

// ---------------------------------------------------------------------------
// Kernel 4: p = tanh([read,k]@fW+fb)@pW + pb. 1024 blocks x 256 thr,
// 64 outputs/block. lane = f-column d; fW column in 128 VGPRs; read/k rows
// staged in LDS (broadcast reads); p via full-wave shfl reduce.
// ---------------------------------------------------------------------------
__global__ __launch_bounds__(256, 2) void k_final(
    const float* __restrict__ readv, const int* __restrict__ skill,
    const float* __restrict__ k_emb,
    const float* __restrict__ fW, const float* __restrict__ fb,
    const float* __restrict__ pW, const float* __restrict__ pb,
    float* __restrict__ out)
{
    __shared__ float rst[64][64];
    __shared__ float kst[64][64];
    __shared__ float pbuf[64];
    const int tid = threadIdx.x;
    const int g = blockIdx.x;
    #pragma unroll
    for (int p = 0; p < 4; ++p) {
        const int r = p * 16 + (tid >> 4);
        int o = g * 64 + r;
        if (o >= NOUT) o = 0;                       // clamp (last block only)
        const int b = o / (SS - 1);
        const int s = o - b * (SS - 1) + 1;         // 1..2047
        const size_t tok = (size_t)b * SS + s;
        const int q = tid & 15;
        *(float4*)&rst[r][q * 4] = ((const float4*)(readv + tok * DD))[q];
        *(float4*)&kst[r][q * 4] = ((const float4*)(k_emb + (size_t)skill[tok] * DD))[q];
    }
    const int l = tid & 63;
    const int w = tid >> 6;
    float fw[128];
    #pragma unroll
    for (int i = 0; i < 128; ++i) fw[i] = fW[i * DD + l];   // coalesced
    const float fbd = fb[l], pwd = pW[l];
    __syncthreads();

    for (int j = 0; j < 16; ++j) {
        const int tl = w * 16 + j;
        const float4* rp = (const float4*)&rst[tl][0];
        const float4* kp = (const float4*)&kst[tl][0];
        float f0 = fbd, f1 = 0.f, f2 = 0.f, f3 = 0.f;
        #pragma unroll
        for (int q = 0; q < 16; ++q) {
            const float4 rv = rp[q];
            f0 = fmaf(rv.x, fw[4*q+0], f0);
            f1 = fmaf(rv.y, fw[4*q+1], f1);
            f2 = fmaf(rv.z, fw[4*q+2], f2);
            f3 = fmaf(rv.w, fw[4*q+3], f3);
        }
        #pragma unroll
        for (int q = 0; q < 16; ++q) {
            const float4 kv = kp[q];
            f0 = fmaf(kv.x, fw[64+4*q+0], f0);
            f1 = fmaf(kv.y, fw[64+4*q+1], f1);
            f2 = fmaf(kv.z, fw[64+4*q+2], f2);
            f3 = fmaf(kv.w, fw[64+4*q+3], f3);
        }
        float pv = tanhf_((f0 + f1) + (f2 + f3)) * pwd;
        #pragma unroll
        for (int off = 32; off >= 1; off >>= 1) pv += __shfl_xor(pv, off);
        if (l == 0) pbuf[tl] = pv;
    }
    __syncthreads();
    if (tid < 64) {
        const int o = g * 64 + tid;
        if (o < NOUT) out[o] = pbuf[tid] + pb[0];
    }
}

// ---------------------------------------------------------------------------
extern "C" void kernel_launch(void* const* d_in, const int* in_sizes, int n_in,
                              void* d_out, int out_size, void* d_ws, size_t ws_size,
                              hipStream_t stream)
{
    const int*   response = (const int*)d_in[1];
    const int*   skill    = (const int*)d_in[2];
    const float* mask     = (const float*)d_in[3];
    const float* k_emb    = (const float*)d_in[4];
    const float* v_emb    = (const float*)d_in[5];
    const float* Mk       = (const float*)d_in[6];
    const float* Mv0      = (const float*)d_in[7];
    const float* eW       = (const float*)d_in[8];
    const float* ebias    = (const float*)d_in[9];
    const float* aW       = (const float*)d_in[10];
    const float* abias    = (const float*)d_in[11];
    const float* fW       = (const float*)d_in[12];
    const float* fbias    = (const float*)d_in[13];
    const float* pW       = (const float*)d_in[14];
    const float* pbias    = (const float*)d_in[15];
    float* out = (float*)d_out;

    // workspace layout (floats); total 23,068,672 floats = 88.0 MiB
    float* ws    = (float*)d_ws;
    float* w_    = ws;                               // B*S*M   = 2,097,152
    float* e_    = w_    + (size_t)BB * SS * MM;     // B*S*D   = 4,194,304
    float* a_    = e_    + (size_t)BB * SS * DD;
    float* Abar  = a_    + (size_t)BB * SS * DD;     // B*C*M*D = 4,194,304
    float* Bbar  = Abar  + (size_t)BB * CC * MM * DD; // doubles as cstate
    float* readv = Bbar  + (size_t)BB * CC * MM * DD; // B*S*D (row s=0 unused)

    k_front<<<1024, 256, 0, stream>>>(skill, response, k_emb, v_emb, Mk,
                                      eW, ebias, aW, abias, mask,
                                      w_, e_, a_, Abar, Bbar);
    k_pass2<<<256,  256, 0, stream>>>(Abar, Bbar, Mv0);
    k_pass3<<<BB * CC * 2, 64, 0, stream>>>(w_, mask, e_, a_, Bbar, readv);
    k_final<<<1024, 256, 0, stream>>>(readv, skill, k_emb, fW, fbias,
                                      pW, pbias, out);
}

// Round 15
// 202.296 us; speedup vs baseline: 4.8913x; 4.8913x over previous
//
#include <hip/hip_runtime.h>
#include <hip/hip_bf16.h>
#include <math.h>

// Problem constants (fixed by the reference)
#define BB 32      // batch
#define SS 2048    // seq len
#define DD 64      // dim_s
#define MM 32      // size_m
#define NSKILL 4096
#define CC 64      // scan chunks
#define LL 32      // chunk length = SS/CC
#define NOUT (BB * (SS - 1))   // 65504

__device__ __forceinline__ float sigmoidf_(float x) {
    return 1.f / (1.f + __expf(-x));
}
__device__ __forceinline__ float tanhf_(float x) {
    float t = __expf(-2.f * fabsf(x));
    float r = (1.f - t) / (1.f + t);
    return copysignf(r, x);
}

// ---------------------------------------------------------------------------
// Kernel 1 (k_front v4): round-11 compute shape (W; EA with ew[64]+aw[64]
// both live in ONE loop -> compiled at 124 VGPR, no spill), but the 32KB
// ea_lds is gone: e -> e_lds (16KB), a -> overwrites the consumed v-row in
// stage (same wave owns the row; LDS same-wave ops are issue-ordered).
// Exchange: ch0 via e_lds (waves 0->1), ch1 via stage (waves 2->3).
// LDS 56.25K -> 40.25K => 3 blocks/CU (was 2).
// r12/r13 lesson: the wcol-reload + er/ar-register restructure caused
// scratch demotion (FETCH 600MB, WRITE 1.2GB) regardless of launch bounds.
// ---------------------------------------------------------------------------
__global__ __launch_bounds__(256, 2) void k_front(
    const int* __restrict__ skill, const int* __restrict__ resp,
    const float* __restrict__ k_emb, const float* __restrict__ v_emb,
    const float* __restrict__ Mk,
    const float* __restrict__ eW, const float* __restrict__ eb,
    const float* __restrict__ aW, const float* __restrict__ ab,
    const float* __restrict__ mask,
    float* __restrict__ w_out, float* __restrict__ e_out, float* __restrict__ a_out,
    float* __restrict__ Abar, float* __restrict__ Bbar)
{
    __shared__ float stage[64 * 64];     // k rows -> v rows -> a vals -> xch ch1
    __shared__ float e_lds[64 * 64];     // e vals -> xch ch0
    __shared__ float w_lds[64 * 32];
    __shared__ float mk_lds[64];
    const int tid = threadIdx.x;
    const int g = blockIdx.x;            // 64-token group
    const int l = tid & 63;
    const int wv = tid >> 6;

    if (tid < 64) mk_lds[tid] = mask[g * 64 + tid];

    // ---- stage k rows (64 x 64) ----
    #pragma unroll
    for (int p = 0; p < 4; ++p) {
        const int r = p * 16 + (tid >> 4);
        const int t = g * 64 + r;
        const float4 kv = ((const float4*)(k_emb + (size_t)skill[t] * DD))[tid & 15];
        *(float4*)&stage[r * 64 + (tid & 15) * 4] = kv;
    }
    __syncthreads();

    // ---- W phase: lane = (m, token-half), 16 tokens per wave ----
    {
        const int m  = l & 31;
        const int th = l >> 5;
        float4 mk4[16];
        const float4* mkp = (const float4*)(Mk + m * DD);
        #pragma unroll
        for (int q = 0; q < 16; ++q) mk4[q] = mkp[q];

        for (int j = 0; j < 8; ++j) {
            const int tl = wv * 16 + j * 2 + th;
            const float4* kp = (const float4*)&stage[tl * 64];
            float a0 = 0.f, a1 = 0.f, a2 = 0.f, a3 = 0.f;
            #pragma unroll
            for (int q = 0; q < 16; ++q) {
                const float4 kv = kp[q];                 // uniform broadcast
                a0 = fmaf(kv.x, mk4[q].x, a0);
                a1 = fmaf(kv.y, mk4[q].y, a1);
                a2 = fmaf(kv.z, mk4[q].z, a2);
                a3 = fmaf(kv.w, mk4[q].w, a3);
            }
            const float lg = (a0 + a1) + (a2 + a3);
            float mx = lg;
            #pragma unroll
            for (int off = 16; off >= 1; off >>= 1) mx = fmaxf(mx, __shfl_xor(mx, off));
            const float ev = __expf(lg - mx);
            float sm = ev;
            #pragma unroll
            for (int off = 16; off >= 1; off >>= 1) sm += __shfl_xor(sm, off);
            w_lds[tl * 32 + m] = ev / sm;
        }
    }
    __syncthreads();   // w_lds complete; all waves done reading k-stage

    // coalesced global store of w (2048 floats)
    #pragma unroll
    for (int i = 0; i < 8; ++i) {
        const int idx = i * 256 + tid;
        w_out[(size_t)g * 2048 + idx] = w_lds[idx];
    }

    // ---- stage v rows (overwrite k-stage) ----
    #pragma unroll
    for (int p = 0; p < 4; ++p) {
        const int r = p * 16 + (tid >> 4);
        const int t = g * 64 + r;
        const int xc = skill[t] + NSKILL * resp[t];
        const float4 vv = ((const float4*)(v_emb + (size_t)xc * DD))[tid & 15];
        *(float4*)&stage[r * 64 + (tid & 15) * 4] = vv;
    }
    __syncthreads();

    // ---- EA phase (r11 shape): lane = d; ew/aw both live in one loop ----
    {
        float ew[64], aw[64];
        #pragma unroll
        for (int i = 0; i < 64; ++i) ew[i] = eW[i * DD + l];   // coalesced
        #pragma unroll
        for (int i = 0; i < 64; ++i) aw[i] = aW[i * DD + l];
        const float ebd = eb[l], abd = ab[l];

        for (int j = 0; j < 16; ++j) {
            const int tl = wv * 16 + j;
            const float4* vp = (const float4*)&stage[tl * 64];
            float e0 = ebd, e1 = 0.f, e2 = 0.f, e3 = 0.f;
            float x0 = abd, x1 = 0.f, x2 = 0.f, x3 = 0.f;
            #pragma unroll
            for (int q = 0; q < 16; ++q) {
                const float4 vv = vp[q];                 // uniform broadcast
                e0 = fmaf(vv.x, ew[4*q+0], e0);
                e1 = fmaf(vv.y, ew[4*q+1], e1);
                e2 = fmaf(vv.z, ew[4*q+2], e2);
                e3 = fmaf(vv.w, ew[4*q+3], e3);
                x0 = fmaf(vv.x, aw[4*q+0], x0);
                x1 = fmaf(vv.y, aw[4*q+1], x1);
                x2 = fmaf(vv.z, aw[4*q+2], x2);
                x3 = fmaf(vv.w, aw[4*q+3], x3);
            }
            const float es = sigmoidf_((e0 + e1) + (e2 + e3));
            const float as = tanhf_((x0 + x1) + (x2 + x3));
            const size_t t = (size_t)(g * 64 + tl);
            e_out[t * DD + l] = es;                      // 256B contiguous
            a_out[t * DD + l] = as;
            e_lds[tl * 64 + l] = es;
            stage[tl * 64 + l] = as;   // own row, all its reads already issued
        }
    }

    // ---- Compose phase: wave wv owns tokens wv*16..+15 (its own e/a rows) ----
    float Ab[32], Bb[32];
    #pragma unroll
    for (int i = 0; i < 32; ++i) { Ab[i] = 1.f; Bb[i] = 0.f; }

    for (int j = 0; j < 16; ++j) {
        const int t = wv * 16 + j;
        const float ed = e_lds[t * 64 + l];              // lane-consecutive
        const float ad = stage[t * 64 + l];
        const float msk = (mk_lds[t] == 1.f) ? 1.f : 0.f;
        const float4* wr = (const float4*)&w_lds[t * 32];
        #pragma unroll
        for (int u = 0; u < 8; ++u) {
            float4 wq = wr[u];                           // uniform broadcast
            wq.x *= msk; wq.y *= msk; wq.z *= msk; wq.w *= msk;
            float t1;
            t1 = fmaf(-wq.x, ed, 1.f); Ab[4*u+0] *= t1; Bb[4*u+0] = fmaf(Bb[4*u+0], t1, wq.x * ad);
            t1 = fmaf(-wq.y, ed, 1.f); Ab[4*u+1] *= t1; Bb[4*u+1] = fmaf(Bb[4*u+1], t1, wq.y * ad);
            t1 = fmaf(-wq.z, ed, 1.f); Ab[4*u+2] *= t1; Bb[4*u+2] = fmaf(Bb[4*u+2], t1, wq.z * ad);
            t1 = fmaf(-wq.w, ed, 1.f); Ab[4*u+3] *= t1; Bb[4*u+3] = fmaf(Bb[4*u+3], t1, wq.w * ad);
        }
    }
    __syncthreads();   // e_lds/stage dead everywhere -> reuse as exchange bufs

    // ---- exchange (parallel): ch0 via e_lds (wv0->wv1), ch1 via stage ----
    if (wv == 0) {
        #pragma unroll
        for (int i = 0; i < 32; ++i) {
            e_lds[i * 64 + l]        = Ab[i];
            e_lds[2048 + i * 64 + l] = Bb[i];
        }
    }
    if (wv == 2) {
        #pragma unroll
        for (int i = 0; i < 32; ++i) {
            stage[i * 64 + l]        = Ab[i];
            stage[2048 + i * 64 + l] = Bb[i];
        }
    }
    __syncthreads();
    if (wv == 1) {
        const size_t base = ((size_t)g * 2 + 0) * (MM * DD);
        #pragma unroll
        for (int i = 0; i < 32; ++i) {
            const float Aa = e_lds[i * 64 + l];
            const float Ba = e_lds[2048 + i * 64 + l];
            Abar[base + i * 64 + l] = Aa * Ab[i];                  // coalesced
            Bbar[base + i * 64 + l] = fmaf(Ba, Ab[i], Bb[i]);
        }
    }
    if (wv == 3) {
        const size_t base = ((size_t)g * 2 + 1) * (MM * DD);
        #pragma unroll
        for (int i = 0; i < 32; ++i) {
            const float Aa = stage[i * 64 + l];
            const float Ba = stage[2048 + i * 64 + l];
            Abar[base + i * 64 + l] = Aa * Ab[i];
            Bbar[base + i * 64 + l] = fmaf(Ba, Ab[i], Bb[i]);
        }
    }
}

// ---------------------------------------------------------------------------
// Kernel 2 (scan pass 2): sequential over 64 chunks, parallel over B*M*D.
// Unroll x4: batch 8 independent loads per 4 dependent FMAs. Writes
// chunk-start states IN PLACE into Bbar.
// ---------------------------------------------------------------------------
__global__ __launch_bounds__(256, 2) void k_pass2(
    const float* __restrict__ Abar, float* __restrict__ Bbar_cst,
    const float* __restrict__ Mv0)
{
    const int idx = blockIdx.x * 256 + threadIdx.x;   // over B*M*D = 65536
    const int b = idx >> 11;
    const int md = idx & 2047;
    float s = Mv0[md];
    for (int c = 0; c < CC; c += 4) {
        const int o0 = ((b * CC + c) << 11) + md;
        const float sa0 = Abar[o0];
        const float sb0 = Bbar_cst[o0];
        const float sa1 = Abar[o0 + 2048];
        const float sb1 = Bbar_cst[o0 + 2048];
        const float sa2 = Abar[o0 + 4096];
        const float sb2 = Bbar_cst[o0 + 4096];
        const float sa3 = Abar[o0 + 6144];
        const float sb3 = Bbar_cst[o0 + 6144];
        Bbar_cst[o0]        = s; s = fmaf(s, sa0, sb0);
        Bbar_cst[o0 + 2048] = s; s = fmaf(s, sa1, sb1);
        Bbar_cst[o0 + 4096] = s; s = fmaf(s, sa2, sb2);
        Bbar_cst[o0 + 6144] = s; s = fmaf(s, sa3, sb3);
    }
}

// ---------------------------------------------------------------------------
// Kernel 3 (scan pass 3, d-split): 2 blocks per (b,chunk). lane=(m-half, d-off);
// Mv[16]/lane; read partials folded across m-halves with shfl_xor(32).
// ---------------------------------------------------------------------------
__global__ __launch_bounds__(64, 4) void k_pass3(
    const float* __restrict__ w, const float* __restrict__ mask,
    const float* __restrict__ e, const float* __restrict__ a,
    const float* __restrict__ cstate, float* __restrict__ readv)
{
    __shared__ float4 wl[LL * MM / 4];   // masked w  (full 32 m)
    __shared__ float4 wn[LL * MM / 4];   // unmasked w, t+1
    const int lane = threadIdx.x;
    const int bc = blockIdx.x >> 1;
    const int dh = blockIdx.x & 1;
    const int b = bc / CC;
    const int c = bc % CC;
    const int t0 = c * LL;
    const bool last = (c == CC - 1);
    const int dof = lane & 31;
    const int mh  = lane >> 5;

    const float4* wg  = (const float4*)(w + (size_t)(b * SS + t0) * MM);
    const float4* wg2 = (const float4*)(w + (size_t)(b * SS + t0 + 1) * MM);
    #pragma unroll
    for (int u = 0; u < 4; ++u) {
        const int q4 = u * 64 + lane;
        const int j = q4 >> 3;
        const float s = (mask[b * SS + t0 + j] == 1.f) ? 1.f : 0.f;
        float4 wq = wg[q4];
        wq.x *= s; wq.y *= s; wq.z *= s; wq.w *= s;
        wl[q4] = wq;
        float4 wq2;
        if (last && q4 >= 248) wq2 = make_float4(0.f, 0.f, 0.f, 0.f);
        else                   wq2 = wg2[q4];
        wn[q4] = wq2;
    }
    __syncthreads();

    float Mv[16];
    const float* cs = cstate + (size_t)bc * MM * DD + (size_t)(mh * 16) * DD
                      + dh * 32 + dof;
    #pragma unroll
    for (int i = 0; i < 16; ++i) Mv[i] = cs[i * DD];

    const float* ep = e + (size_t)(b * SS + t0) * DD + dh * 32 + dof;
    const float* ap = a + (size_t)(b * SS + t0) * DD + dh * 32 + dof;
    float* ro = readv + (size_t)(b * SS + t0 + 1) * DD + dh * 32 + dof;
    for (int j = 0; j < LL; ++j) {
        const float ed = ep[j * DD];
        const float ad = ap[j * DD];
        const float4* wlj = wl + j * 8 + mh * 4;
        const float4* wnj = wn + j * 8 + mh * 4;
        float r0 = 0.f, r1 = 0.f, r2 = 0.f, r3 = 0.f;
        #pragma unroll
        for (int u = 0; u < 4; ++u) {
            const float4 wq = wlj[u];
            const float4 w2 = wnj[u];
            float t1;
            t1 = fmaf(-wq.x, ed, 1.f); Mv[4*u+0] = fmaf(Mv[4*u+0], t1, wq.x * ad); r0 = fmaf(w2.x, Mv[4*u+0], r0);
            t1 = fmaf(-wq.y, ed, 1.f); Mv[4*u+1] = fmaf(Mv[4*u+1], t1, wq.y * ad); r1 = fmaf(w2.y, Mv[4*u+1], r1);
            t1 = fmaf(-wq.z, ed, 1.f); Mv[4*u+2] = fmaf(Mv[4*u+2], t1, wq.z * ad); r2 = fmaf(w2.z, Mv[4*u+2], r2);
            t1 = fmaf(-wq.w, ed, 1.f); Mv[4*u+3] = fmaf(Mv[4*u+3], t1, wq.w * ad); r3 = fmaf(w2.w, Mv[4*u+3], r3);
        }
        float r = (r0 + r1) + (r2 + r3);
        r += __shfl_xor(r, 32);              // fold the two m-halves
        if (mh == 0 && !(last && j == LL - 1))
            ro[j * DD] = r;
    }
}

// ---------------------------------------------------------------------------
// Kernel 4: p = tanh([read,k]@fW+fb)@pW + pb. 1024 blocks x 256 thr,
// 64 outputs/block. lane = f-column d; fW column in 128 VGPRs; read/k rows
// staged in LDS (broadcast reads); p via full-wave shfl reduce.
// ---------------------------------------------------------------------------
__global__ __launch_bounds__(256, 2) void k_final(
    const float* __restrict__ readv, const int* __restrict__ skill,
    const float* __restrict__ k_emb,
    const float* __restrict__ fW, const float* __restrict__ fb,
    const float* __restrict__ pW, const float* __restrict__ pb,
    float* __restrict__ out)
{
    __shared__ float rst[64][64];
    __shared__ float kst[64][64];
    __shared__ float pbuf[64];
    const int tid = threadIdx.x;
    const int g = blockIdx.x;
    #pragma unroll
    for (int p = 0; p < 4; ++p) {
        const int r = p * 16 + (tid >> 4);
        int o = g * 64 + r;
        if (o >= NOUT) o = 0;                       // clamp (last block only)
        const int b = o / (SS - 1);
        const int s = o - b * (SS - 1) + 1;         // 1..2047
        const size_t tok = (size_t)b * SS + s;
        const int q = tid & 15;
        *(float4*)&rst[r][q * 4] = ((const float4*)(readv + tok * DD))[q];
        *(float4*)&kst[r][q * 4] = ((const float4*)(k_emb + (size_t)skill[tok] * DD))[q];
    }
    const int l = tid & 63;
    const int w = tid >> 6;
    float fw[128];
    #pragma unroll
    for (int i = 0; i < 128; ++i) fw[i] = fW[i * DD + l];   // coalesced
    const float fbd = fb[l], pwd = pW[l];
    __syncthreads();

    for (int j = 0; j < 16; ++j) {
        const int tl = w * 16 + j;
        const float4* rp = (const float4*)&rst[tl][0];
        const float4* kp = (const float4*)&kst[tl][0];
        float f0 = fbd, f1 = 0.f, f2 = 0.f, f3 = 0.f;
        #pragma unroll
        for (int q = 0; q < 16; ++q) {
            const float4 rv = rp[q];
            f0 = fmaf(rv.x, fw[4*q+0], f0);
            f1 = fmaf(rv.y, fw[4*q+1], f1);
            f2 = fmaf(rv.z, fw[4*q+2], f2);
            f3 = fmaf(rv.w, fw[4*q+3], f3);
        }
        #pragma unroll
        for (int q = 0; q < 16; ++q) {
            const float4 kv = kp[q];
            f0 = fmaf(kv.x, fw[64+4*q+0], f0);
            f1 = fmaf(kv.y, fw[64+4*q+1], f1);
            f2 = fmaf(kv.z, fw[64+4*q+2], f2);
            f3 = fmaf(kv.w, fw[64+4*q+3], f3);
        }
        float pv = tanhf_((f0 + f1) + (f2 + f3)) * pwd;
        #pragma unroll
        for (int off = 32; off >= 1; off >>= 1) pv += __shfl_xor(pv, off);
        if (l == 0) pbuf[tl] = pv;
    }
    __syncthreads();
    if (tid < 64) {
        const int o = g * 64 + tid;
        if (o < NOUT) out[o] = pbuf[tid] + pb[0];
    }
}

// ---------------------------------------------------------------------------
extern "C" void kernel_launch(void* const* d_in, const int* in_sizes, int n_in,
                              void* d_out, int out_size, void* d_ws, size_t ws_size,
                              hipStream_t stream)
{
    const int*   response = (const int*)d_in[1];
    const int*   skill    = (const int*)d_in[2];
    const float* mask     = (const float*)d_in[3];
    const float* k_emb    = (const float*)d_in[4];
    const float* v_emb    = (const float*)d_in[5];
    const float* Mk       = (const float*)d_in[6];
    const float* Mv0      = (const float*)d_in[7];
    const float* eW       = (const float*)d_in[8];
    const float* ebias    = (const float*)d_in[9];
    const float* aW       = (const float*)d_in[10];
    const float* abias    = (const float*)d_in[11];
    const float* fW       = (const float*)d_in[12];
    const float* fbias    = (const float*)d_in[13];
    const float* pW       = (const float*)d_in[14];
    const float* pbias    = (const float*)d_in[15];
    float* out = (float*)d_out;

    // workspace layout (floats); total 23,068,672 floats = 88.0 MiB
    float* ws    = (float*)d_ws;
    float* w_    = ws;                               // B*S*M   = 2,097,152
    float* e_    = w_    + (size_t)BB * SS * MM;     // B*S*D   = 4,194,304
    float* a_    = e_    + (size_t)BB * SS * DD;
    float* Abar  = a_    + (size_t)BB * SS * DD;     // B*C*M*D = 4,194,304
    float* Bbar  = Abar  + (size_t)BB * CC * MM * DD; // doubles as cstate
    float* readv = Bbar  + (size_t)BB * CC * MM * DD; // B*S*D (row s=0 unused)

    k_front<<<1024, 256, 0, stream>>>(skill, response, k_emb, v_emb, Mk,
                                      eW, ebias, aW, abias, mask,
                                      w_, e_, a_, Abar, Bbar);
    k_pass2<<<256,  256, 0, stream>>>(Abar, Bbar, Mv0);
    k_pass3<<<BB * CC * 2, 64, 0, stream>>>(w_, mask, e_, a_, Bbar, readv);
    k_final<<<1024, 256, 0, stream>>>(readv, skill, k_emb, fW, fbias,
                                      pW, pbias, out);
}